// Round 8
// baseline (425.082 us; speedup 1.0000x reference)
//
#include <hip/hip_runtime.h>

#define NXCD 8
#define PA_NB 256   // pa_gemm blocks (partial buffers)

typedef short bf16x8 __attribute__((ext_vector_type(8)));  // 8 bf16 (4 VGPRs)
typedef float f32x4  __attribute__((ext_vector_type(4)));
typedef unsigned int u32x2 __attribute__((ext_vector_type(2)));
typedef unsigned int u32x4 __attribute__((ext_vector_type(4)));

union U4S8 { uint4 u; u32x4 v; bf16x8 s; };

__device__ __forceinline__ unsigned int f2bf(float f) {
    unsigned int u = __float_as_uint(f);
    return (u + 0x7fffu + ((u >> 16) & 1u)) >> 16;   // RNE
}
__device__ __forceinline__ float bflo(unsigned int u) { return __uint_as_float(u << 16); }
__device__ __forceinline__ float bfhi(unsigned int u) { return __uint_as_float(u & 0xffff0000u); }

// nt vector-load helpers (builtin requires vector-of-scalar, not HIP_vector_type)
__device__ __forceinline__ f32x4 nt_ld_f4(const float4* p) {
    return __builtin_nontemporal_load((const f32x4*)p);
}
__device__ __forceinline__ u32x2 nt_ld_u2(const uint2* p) {
    return __builtin_nontemporal_load((const u32x2*)p);
}
__device__ __forceinline__ unsigned int nt_ld_u(const unsigned int* p) {
    return __builtin_nontemporal_load(p);
}

// ---------- features f32 -> bf16 (packed 2/uint) ----------
__global__ __launch_bounds__(256) void fconv(
    const float4* __restrict__ F4, uint4* __restrict__ B4, long long n8)
{
    long long t = (long long)blockIdx.x * 256 + threadIdx.x;
    if (t >= n8) return;
    f32x4 a = nt_ld_f4(&F4[2 * t]);
    f32x4 b = nt_ld_f4(&F4[2 * t + 1]);
    uint4 o;
    o.x = f2bf(a.x) | (f2bf(a.y) << 16);
    o.y = f2bf(a.z) | (f2bf(a.w) << 16);
    o.z = f2bf(b.x) | (f2bf(b.y) << 16);
    o.w = f2bf(b.z) | (f2bf(b.w) << 16);
    B4[t] = o;
}

// ---------- combined edge pass 1: deg histogram (by dst range) + PA counts
// (by src range). nt loads keep the streaming edge lists out of L2 so the
// scatter slices (deg 50KB + PA 800KB + gid 400KB per XCD) stay resident.
__global__ __launch_bounds__(256) void hist_pa_xcd(
    const int* __restrict__ src, const int* __restrict__ dst,
    const int* __restrict__ gid, int* __restrict__ deg,
    unsigned int* __restrict__ PA32, int E, int N)
{
    int x  = blockIdx.x & (NXCD - 1);
    int bi = blockIdx.x >> 3;
    int K  = gridDim.x >> 3;
    int chunk = (N + NXCD - 1) / NXCD;
    int lo = x * chunk;
    int hi = lo + chunk; if (hi > N) hi = N;
    for (int e = bi * 256 + threadIdx.x; e < E; e += K * 256) {
        int d = __builtin_nontemporal_load(&dst[e]);
        int s = __builtin_nontemporal_load(&src[e]);
        if (d >= lo && d < hi) atomicAdd(&deg[d], 1);
        if (s >= lo && s < hi) {
            int g = gid[d];
            atomicAdd(&PA32[(size_t)s * 16 + (g >> 2)], 1u << ((g & 3) * 8));
        }
    }
}

__global__ __launch_bounds__(1024) void scan_partial(
    const int* __restrict__ deg, int* __restrict__ bsums, int N)
{
    __shared__ int sw[16];
    int idx = blockIdx.x * 1024 + threadIdx.x;
    int v = (idx < N) ? deg[idx] : 0;
    #pragma unroll
    for (int o = 32; o; o >>= 1) v += __shfl_down(v, o, 64);
    if ((threadIdx.x & 63) == 0) sw[threadIdx.x >> 6] = v;
    __syncthreads();
    if (threadIdx.x < 16) {
        int x = sw[threadIdx.x];
        #pragma unroll
        for (int o = 8; o; o >>= 1) x += __shfl_down(x, o, 16);
        if (threadIdx.x == 0) bsums[blockIdx.x] = x;
    }
}

__global__ void scan_exclusive_small(int* bsums, int nb)
{
    if (threadIdx.x == 0) {
        int run = 0;
        for (int i = 0; i < nb; ++i) { int t = bsums[i]; bsums[i] = run; run += t; }
    }
}

__global__ __launch_bounds__(1024) void scan_final(
    const int* __restrict__ deg, const int* __restrict__ bsums,
    int* __restrict__ off, int N)
{
    __shared__ int s[1024];
    int t = threadIdx.x;
    int idx = blockIdx.x * 1024 + t;
    int v = (idx < N) ? deg[idx] : 0;
    s[t] = v;
    __syncthreads();
    #pragma unroll
    for (int o = 1; o < 1024; o <<= 1) {
        int x = (t >= o) ? s[t - o] : 0;
        __syncthreads();
        s[t] += x;
        __syncthreads();
    }
    if (idx <= N) off[idx] = s[t] - v + bsums[blockIdx.x];
}

__global__ __launch_bounds__(256) void fill_xcd(
    const int* __restrict__ src, const int* __restrict__ dst,
    int* __restrict__ cursor, int* __restrict__ col, int E, int N)
{
    int x  = blockIdx.x & (NXCD - 1);
    int bi = blockIdx.x >> 3;
    int K  = gridDim.x >> 3;
    int chunk = (N + NXCD - 1) / NXCD;
    int lo = x * chunk;
    int hi = lo + chunk; if (hi > N) hi = N;
    for (int e = bi * 256 + threadIdx.x; e < E; e += K * 256) {
        int d = __builtin_nontemporal_load(&dst[e]);
        int s = __builtin_nontemporal_load(&src[e]);
        if (d >= lo && d < hi) {
            int pos = atomicAdd(&cursor[d], 1);
            col[pos] = s;
        }
    }
}

// ---------- bf16 CSR gather: t[v] = sum_{e: dst=v} X[col[e]], bf16 out ----------
__global__ __launch_bounds__(256) void csr_agg_bf16(
    const uint4* __restrict__ X, const int* __restrict__ off,
    const int* __restrict__ col, uint4* __restrict__ T, int N)
{
    int v = blockIdx.x * 16 + (threadIdx.x >> 4);
    if (v >= N) return;
    int lane = threadIdx.x & 15;
    int beg = off[v], end = off[v + 1];
    float a0=0,a1=0,a2=0,a3=0,a4=0,a5=0,a6=0,a7=0;
    #define ACCUM(u) { \
        a0 += bflo((u).x); a1 += bfhi((u).x); \
        a2 += bflo((u).y); a3 += bfhi((u).y); \
        a4 += bflo((u).z); a5 += bfhi((u).z); \
        a6 += bflo((u).w); a7 += bfhi((u).w); }
    int i = beg;
    for (; i + 1 < end; i += 2) {
        int c0 = __builtin_nontemporal_load(&col[i]);
        int c1 = __builtin_nontemporal_load(&col[i + 1]);
        uint4 x0 = X[(size_t)c0 * 16 + lane];
        uint4 x1 = X[(size_t)c1 * 16 + lane];
        ACCUM(x0) ACCUM(x1)
    }
    if (i < end) {
        int c0 = __builtin_nontemporal_load(&col[i]);
        uint4 x0 = X[(size_t)c0 * 16 + lane];
        ACCUM(x0)
    }
    #undef ACCUM
    uint4 o;
    o.x = f2bf(a0) | (f2bf(a1) << 16);
    o.y = f2bf(a2) | (f2bf(a3) << 16);
    o.z = f2bf(a4) | (f2bf(a5) << 16);
    o.w = f2bf(a6) | (f2bf(a7) << 16);
    T[(size_t)v * 16 + lane] = o;
}

// ---------- MFMA GEMM: Y = relu(T @ W1), Y in fragment-native bf16 layout ----------
__global__ __launch_bounds__(256) void gemm_mfma(
    const uint4* __restrict__ T, const float* __restrict__ W,
    uint2* __restrict__ Y, int N, int RB)
{
    __shared__ char sWT[32768];
    int t = threadIdx.x;
    {
        int c = t & 127;
        int xo = (c & 7) << 4;
        #pragma unroll
        for (int i = 0; i < 8; ++i) {
            int kc = (t >> 7) + 2 * i;   // 0..15
            int k0 = kc * 8;
            unsigned int h[8];
            #pragma unroll
            for (int j = 0; j < 8; ++j)
                h[j] = f2bf(W[(k0 + j) * 128 + c]);
            uint4 pk;
            pk.x = h[0] | (h[1] << 16);
            pk.y = h[2] | (h[3] << 16);
            pk.z = h[4] | (h[5] << 16);
            pk.w = h[6] | (h[7] << 16);
            *(uint4*)(sWT + c * 256 + ((k0 * 2) ^ xo)) = pk;
        }
    }
    __syncthreads();

    int wid = t >> 6, l = t & 63;
    int rb = blockIdx.x * 4 + wid;
    if (rb >= RB) return;
    int lrow = l & 15, lg = l >> 4;
    int row = rb * 16 + lrow;

    U4S8 cv;
    bf16x8 a[4];
    #pragma unroll
    for (int kk = 0; kk < 4; ++kk) {
        cv.u = (row < N) ? T[(size_t)row * 16 + kk * 4 + lg] : make_uint4(0,0,0,0);
        a[kk] = cv.s;
    }

    f32x4 acc[8];
    #pragma unroll
    for (int ct = 0; ct < 8; ++ct) acc[ct] = (f32x4){0.f,0.f,0.f,0.f};

    #pragma unroll
    for (int ct = 0; ct < 8; ++ct) {
        int c = ct * 16 + lrow;
        const char* base = sWT + c * 256;
        int xo = (c & 7) << 4;
        #pragma unroll
        for (int kk = 0; kk < 4; ++kk) {
            cv.u = *(const uint4*)(base + ((kk * 64 + lg * 16) ^ xo));
            acc[ct] = __builtin_amdgcn_mfma_f32_16x16x32_bf16(a[kk], cv.s, acc[ct], 0, 0, 0);
        }
    }

    #pragma unroll
    for (int ct = 0; ct < 8; ++ct) {
        uint2 o;
        o.x = f2bf(fmaxf(acc[ct][0], 0.f)) | (f2bf(fmaxf(acc[ct][1], 0.f)) << 16);
        o.y = f2bf(fmaxf(acc[ct][2], 0.f)) | (f2bf(fmaxf(acc[ct][3], 0.f)) << 16);
        Y[((size_t)rb * 8 + ct) * 64 + l] = o;
    }
}

// ---------- pa_gemm: partial[b][g][c] = sum_{v in chunk} count(v,g) * Y[v][c] ----------
__global__ __launch_bounds__(256) void pa_gemm(
    const uint2* __restrict__ Ybf, const unsigned int* __restrict__ PA32,
    float4* __restrict__ partial, int N, int chunk)
{
    __shared__ float sY[8 * 128];
    __shared__ unsigned int sPA[8 * 16];

    int b = blockIdx.x;
    int v0 = b * chunk;
    int v1 = v0 + chunk; if (v1 > N) v1 = N;

    int t = threadIdx.x;
    int j = t & 15, dgrp = t >> 4;
    float4 acc[4][2];
    #pragma unroll
    for (int i = 0; i < 4; ++i) { acc[i][0] = make_float4(0,0,0,0); acc[i][1] = make_float4(0,0,0,0); }

    int ctS = t >> 5, lsub = t & 31;        // staging coords
    int vlocS = (lsub >> 4) * 4;
    int cS = ctS * 16 + (lsub & 15);

    for (int vc = v0; vc < v1; vc += 8) {
        {
            int rb = vc >> 4, qb = vc & 15; // qb in {0,8}
            u32x2 u = nt_ld_u2(&Ybf[((size_t)rb * 8 + ctS) * 64 + (qb >> 2) * 16 + lsub]);
            sY[(vlocS + 0) * 128 + cS] = bflo(u.x);
            sY[(vlocS + 1) * 128 + cS] = bfhi(u.x);
            sY[(vlocS + 2) * 128 + cS] = bflo(u.y);
            sY[(vlocS + 3) * 128 + cS] = bfhi(u.y);
        }
        if (t < 128) {
            int vp = vc + (t >> 4);
            sPA[t] = (vp < v1) ? nt_ld_u(&PA32[(size_t)vp * 16 + (t & 15)]) : 0u;
        }
        __syncthreads();
        const float4* sY4 = (const float4*)sY;
        #pragma unroll
        for (int vv = 0; vv < 8; ++vv) {
            unsigned int pw = sPA[vv * 16 + j];
            float4 y0 = sY4[vv * 32 + dgrp * 2 + 0];
            float4 y1 = sY4[vv * 32 + dgrp * 2 + 1];
            #pragma unroll
            for (int i = 0; i < 4; ++i) {
                float w = (float)((pw >> (i * 8)) & 0xffu);
                acc[i][0].x += w * y0.x; acc[i][0].y += w * y0.y;
                acc[i][0].z += w * y0.z; acc[i][0].w += w * y0.w;
                acc[i][1].x += w * y1.x; acc[i][1].y += w * y1.y;
                acc[i][1].z += w * y1.z; acc[i][1].w += w * y1.w;
            }
        }
        __syncthreads();
    }

    #pragma unroll
    for (int i = 0; i < 4; ++i) {
        int g = j * 4 + i;
        partial[(size_t)b * 2048 + g * 32 + dgrp * 2 + 0] = acc[i][0];
        partial[(size_t)b * 2048 + g * 32 + dgrp * 2 + 1] = acc[i][1];
    }
}

__global__ __launch_bounds__(256) void reduce_partial(
    const float* __restrict__ partial, float* __restrict__ pooled)
{
    int o = blockIdx.x * 256 + threadIdx.x; // 0..8191
    float s = 0.f;
    #pragma unroll 4
    for (int b = 0; b < PA_NB; ++b)
        s += partial[(size_t)b * 8192 + o];
    pooled[o] = s;
}

// ---------- fused tail: W23 = W2@W3 (LDS); out = sigmoid((pooled/cnt)@W23) ----------
__global__ __launch_bounds__(1024) void final_fused(
    const float* __restrict__ pooled, const int* __restrict__ gid, int N,
    const float* __restrict__ W2, const float* __restrict__ W3,
    float* __restrict__ out)
{
    __shared__ float sW23[128 * 16];
    __shared__ int lb[65];
    int t = threadIdx.x;
    if (t <= 64) {
        int lo = 0, hi = N;
        while (lo < hi) { int mid = (lo + hi) >> 1; if (gid[mid] < t) lo = mid + 1; else hi = mid; }
        lb[t] = lo;
    }
    for (int idx = t; idx < 2048; idx += 1024) {
        int k = idx >> 4, o = idx & 15;
        float a = 0.f;
        #pragma unroll 16
        for (int jj = 0; jj < 128; ++jj)
            a += W2[k * 128 + jj] * W3[jj * 16 + o];
        sW23[idx] = a;
    }
    __syncthreads();
    int g = t >> 4, o = t & 15;
    float cnt = fmaxf((float)(lb[g + 1] - lb[g]), 1.0f);
    float acc = 0.f;
    #pragma unroll 16
    for (int k = 0; k < 128; ++k)
        acc += pooled[g * 128 + k] * sW23[k * 16 + o];
    acc /= cnt;
    out[g * 16 + o] = 1.0f / (1.0f + __expf(-acc));
}

extern "C" void kernel_launch(void* const* d_in, const int* in_sizes, int n_in,
                              void* d_out, int out_size, void* d_ws, size_t ws_size,
                              hipStream_t stream)
{
    const float* features = (const float*)d_in[0];
    const float* W1       = (const float*)d_in[1];
    const float* W2       = (const float*)d_in[2];
    const float* W3       = (const float*)d_in[3];
    const int*   src      = (const int*)d_in[4];
    const int*   dst      = (const int*)d_in[5];
    const int*   gid      = (const int*)d_in[6];
    int N = in_sizes[0] / 128;
    int E = in_sizes[4];
    float* out = (float*)d_out;

    int RB = (N + 15) / 16;

    char* ws = (char*)d_ws;
    size_t p = 0;
    auto alloc = [&](size_t bytes) { void* r = ws + p; p = (p + bytes + 255) & ~(size_t)255; return r; };
    unsigned int* fbf  = (unsigned int*)alloc((size_t)N * 128 * 2);     // features bf16
    unsigned int* tbf  = (unsigned int*)alloc((size_t)N * 128 * 2);     // t bf16
    uint2*        Ybf  = (uint2*)alloc((size_t)RB * 8 * 64 * 8);        // Y bf16 frag-native
    unsigned int* PA32 = (unsigned int*)alloc((size_t)N * 16 * 4);      // packed counts
    float* partial = (float*)alloc((size_t)PA_NB * 8192 * 4);           // 8 MB
    float* pooled  = (float*)alloc(64 * 128 * sizeof(float));
    int*   deg     = (int*)alloc((size_t)N * sizeof(int));
    int*   off     = (int*)alloc((size_t)(N + 1) * sizeof(int));
    int*   cursor  = (int*)alloc((size_t)N * sizeof(int));
    int*   col     = (int*)alloc((size_t)E * sizeof(int));
    int*   bsums   = (int*)alloc(256 * sizeof(int));

    int aggGrid  = (N + 15) / 16;
    int scanGrid = (N + 1024) / 1024;
    int xcdGrid  = 1024;
    int gGrid    = (RB + 3) / 4;
    int paChunk  = (((N + PA_NB - 1) / PA_NB) + 15) & ~15;
    long long n8 = (long long)N * 16;

    // ---- features -> bf16 ----
    fconv<<<(int)((n8 + 255) / 256), 256, 0, stream>>>((const float4*)features, (uint4*)fbf, n8);

    // ---- edge pass 1: deg histogram + PA counts ----
    (void)hipMemsetAsync(deg, 0, (size_t)N * sizeof(int), stream);
    (void)hipMemsetAsync(PA32, 0, (size_t)N * 16 * 4, stream);
    hist_pa_xcd<<<xcdGrid, 256, 0, stream>>>(src, dst, gid, deg, PA32, E, N);

    // ---- scan -> off ; edge pass 2: fill col ----
    scan_partial<<<scanGrid, 1024, 0, stream>>>(deg, bsums, N);
    scan_exclusive_small<<<1, 64, 0, stream>>>(bsums, scanGrid);
    scan_final<<<scanGrid, 1024, 0, stream>>>(deg, bsums, off, N);
    (void)hipMemcpyAsync(cursor, off, (size_t)N * sizeof(int), hipMemcpyDeviceToDevice, stream);
    fill_xcd<<<xcdGrid, 256, 0, stream>>>(src, dst, cursor, col, E, N);

    // ---- t = agg(features_bf16) [bf16]; Y = relu(t @ W1) [bf16 frag] ----
    csr_agg_bf16<<<aggGrid, 256, 0, stream>>>((const uint4*)fbf, off, col, (uint4*)tbf, N);
    gemm_mfma<<<gGrid, 256, 0, stream>>>((const uint4*)tbf, W1, Ybf, N, RB);

    // ---- pooled_q = PA^T . Y ----
    pa_gemm<<<PA_NB, 256, 0, stream>>>(Ybf, PA32, (float4*)partial, N, paChunk);
    reduce_partial<<<32, 256, 0, stream>>>(partial, pooled);

    // ---- fused (W2@W3) + mean + sigmoid ----
    final_fused<<<1, 1024, 0, stream>>>(pooled, gid, N, W2, W3, out);
}

// Round 9
// 341.250 us; speedup vs baseline: 1.2457x; 1.2457x over previous
//
#include <hip/hip_runtime.h>

#define NXCD 8
#define PA_NB 256    // pa_gemm blocks (partial buffers)
#define CSLOT 32     // fixed col slots per node (deg ~ Poisson(16))
#define OVCAP 65536  // overflow list capacity (expected use: ~tens)

typedef short bf16x8 __attribute__((ext_vector_type(8)));  // 8 bf16 (4 VGPRs)
typedef float f32x4  __attribute__((ext_vector_type(4)));
typedef unsigned int u32x2 __attribute__((ext_vector_type(2)));
typedef unsigned int u32x4 __attribute__((ext_vector_type(4)));

union U4S8 { uint4 u; u32x4 v; bf16x8 s; };

__device__ __forceinline__ unsigned int f2bf(float f) {
    unsigned int u = __float_as_uint(f);
    return (u + 0x7fffu + ((u >> 16) & 1u)) >> 16;   // RNE
}
__device__ __forceinline__ float bflo(unsigned int u) { return __uint_as_float(u << 16); }
__device__ __forceinline__ float bfhi(unsigned int u) { return __uint_as_float(u & 0xffff0000u); }

__device__ __forceinline__ f32x4 nt_ld_f4(const float4* p) {
    return __builtin_nontemporal_load((const f32x4*)p);
}
__device__ __forceinline__ u32x2 nt_ld_u2(const uint2* p) {
    return __builtin_nontemporal_load((const u32x2*)p);
}
__device__ __forceinline__ unsigned int nt_ld_u(const unsigned int* p) {
    return __builtin_nontemporal_load(p);
}

// ---------- features f32 -> bf16 (packed 2/uint) ----------
__global__ __launch_bounds__(256) void fconv(
    const float4* __restrict__ F4, uint4* __restrict__ B4, long long n8)
{
    long long t = (long long)blockIdx.x * 256 + threadIdx.x;
    if (t >= n8) return;
    f32x4 a = nt_ld_f4(&F4[2 * t]);
    f32x4 b = nt_ld_f4(&F4[2 * t + 1]);
    uint4 o;
    o.x = f2bf(a.x) | (f2bf(a.y) << 16);
    o.y = f2bf(a.z) | (f2bf(a.w) << 16);
    o.z = f2bf(b.x) | (f2bf(b.y) << 16);
    o.w = f2bf(b.z) | (f2bf(b.w) << 16);
    B4[t] = o;
}

// ---------- fixed-slot CSR fill (no hist/scan needed) ----------
// col[v*CSLOT + pos] = src, pos via per-node atomic counter; rare overflow
// (deg > CSLOT) appended to a small list replayed by csr_agg.
__global__ __launch_bounds__(256) void fillfix_xcd(
    const int* __restrict__ src, const int* __restrict__ dst,
    int* __restrict__ cnt, int* __restrict__ col,
    int* __restrict__ ovd, int* __restrict__ ovs, int* __restrict__ ov_cnt,
    int E, int N)
{
    int x  = blockIdx.x & (NXCD - 1);
    int bi = blockIdx.x >> 3;
    int K  = gridDim.x >> 3;
    int chunk = (N + NXCD - 1) / NXCD;
    int lo = x * chunk;
    int hi = lo + chunk; if (hi > N) hi = N;
    for (int e = bi * 256 + threadIdx.x; e < E; e += K * 256) {
        int d = dst[e];
        int s = src[e];
        if (d >= lo && d < hi) {
            int pos = atomicAdd(&cnt[d], 1);
            if (pos < CSLOT) {
                col[(size_t)d * CSLOT + pos] = s;
            } else {
                int op = atomicAdd(ov_cnt, 1);
                if (op < OVCAP) { ovd[op] = d; ovs[op] = s; }
            }
        }
    }
}

// ---------- PA build: PA32[v][g>>2] byte (g&3) += 1 for each edge v->g ----------
__global__ __launch_bounds__(256) void edge_pa(
    const int* __restrict__ src, const int* __restrict__ dst,
    const int* __restrict__ gid, unsigned int* __restrict__ PA32, int E, int N)
{
    int x  = blockIdx.x & (NXCD - 1);
    int bi = blockIdx.x >> 3;
    int K  = gridDim.x >> 3;
    int chunk = (N + NXCD - 1) / NXCD;
    int lo = x * chunk;
    int hi = lo + chunk; if (hi > N) hi = N;
    for (int e = bi * 256 + threadIdx.x; e < E; e += K * 256) {
        int s = src[e];
        int d = dst[e];
        if (s >= lo && s < hi) {
            int g = gid[d];
            atomicAdd(&PA32[(size_t)s * 16 + (g >> 2)], 1u << ((g & 3) * 8));
        }
    }
}

// ---------- bf16 CSR gather (fixed slots): t[v] = sum X[col[v*CSLOT..]] ----------
__global__ __launch_bounds__(256) void csr_agg_bf16(
    const uint4* __restrict__ X, const int* __restrict__ cnt,
    const int* __restrict__ col,
    const int* __restrict__ ovd, const int* __restrict__ ovs,
    const int* __restrict__ ov_cnt,
    uint4* __restrict__ T, int N)
{
    int v = blockIdx.x * 16 + (threadIdx.x >> 4);
    if (v >= N) return;
    int lane = threadIdx.x & 15;
    int c = cnt[v];
    int end = c < CSLOT ? c : CSLOT;
    const int* cb = col + (size_t)v * CSLOT;
    float a0=0,a1=0,a2=0,a3=0,a4=0,a5=0,a6=0,a7=0;
    #define ACCUM(u) { \
        a0 += bflo((u).x); a1 += bfhi((u).x); \
        a2 += bflo((u).y); a3 += bfhi((u).y); \
        a4 += bflo((u).z); a5 += bfhi((u).z); \
        a6 += bflo((u).w); a7 += bfhi((u).w); }
    int i = 0;
    for (; i + 1 < end; i += 2) {
        int c0 = cb[i], c1 = cb[i + 1];
        uint4 x0 = X[(size_t)c0 * 16 + lane];
        uint4 x1 = X[(size_t)c1 * 16 + lane];
        ACCUM(x0) ACCUM(x1)
    }
    if (i < end) {
        uint4 x0 = X[(size_t)cb[i] * 16 + lane];
        ACCUM(x0)
    }
    // overflow replay (expected ~tens of entries for this graph; usually loops 0-30x)
    int oc = *ov_cnt; if (oc > OVCAP) oc = OVCAP;
    for (int k = 0; k < oc; ++k) {
        if (ovd[k] == v) {
            uint4 x0 = X[(size_t)ovs[k] * 16 + lane];
            ACCUM(x0)
        }
    }
    #undef ACCUM
    uint4 o;
    o.x = f2bf(a0) | (f2bf(a1) << 16);
    o.y = f2bf(a2) | (f2bf(a3) << 16);
    o.z = f2bf(a4) | (f2bf(a5) << 16);
    o.w = f2bf(a6) | (f2bf(a7) << 16);
    T[(size_t)v * 16 + lane] = o;
}

// ---------- MFMA GEMM: Y = relu(T @ W1), Y in fragment-native bf16 layout ----------
__global__ __launch_bounds__(256) void gemm_mfma(
    const uint4* __restrict__ T, const float* __restrict__ W,
    uint2* __restrict__ Y, int N, int RB)
{
    __shared__ char sWT[32768];
    int t = threadIdx.x;
    {
        int c = t & 127;
        int xo = (c & 7) << 4;
        #pragma unroll
        for (int i = 0; i < 8; ++i) {
            int kc = (t >> 7) + 2 * i;   // 0..15
            int k0 = kc * 8;
            unsigned int h[8];
            #pragma unroll
            for (int j = 0; j < 8; ++j)
                h[j] = f2bf(W[(k0 + j) * 128 + c]);
            uint4 pk;
            pk.x = h[0] | (h[1] << 16);
            pk.y = h[2] | (h[3] << 16);
            pk.z = h[4] | (h[5] << 16);
            pk.w = h[6] | (h[7] << 16);
            *(uint4*)(sWT + c * 256 + ((k0 * 2) ^ xo)) = pk;
        }
    }
    __syncthreads();

    int wid = t >> 6, l = t & 63;
    int rb = blockIdx.x * 4 + wid;
    if (rb >= RB) return;
    int lrow = l & 15, lg = l >> 4;
    int row = rb * 16 + lrow;

    U4S8 cv;
    bf16x8 a[4];
    #pragma unroll
    for (int kk = 0; kk < 4; ++kk) {
        cv.u = (row < N) ? T[(size_t)row * 16 + kk * 4 + lg] : make_uint4(0,0,0,0);
        a[kk] = cv.s;
    }

    f32x4 acc[8];
    #pragma unroll
    for (int ct = 0; ct < 8; ++ct) acc[ct] = (f32x4){0.f,0.f,0.f,0.f};

    #pragma unroll
    for (int ct = 0; ct < 8; ++ct) {
        int c = ct * 16 + lrow;
        const char* base = sWT + c * 256;
        int xo = (c & 7) << 4;
        #pragma unroll
        for (int kk = 0; kk < 4; ++kk) {
            cv.u = *(const uint4*)(base + ((kk * 64 + lg * 16) ^ xo));
            acc[ct] = __builtin_amdgcn_mfma_f32_16x16x32_bf16(a[kk], cv.s, acc[ct], 0, 0, 0);
        }
    }

    #pragma unroll
    for (int ct = 0; ct < 8; ++ct) {
        uint2 o;
        o.x = f2bf(fmaxf(acc[ct][0], 0.f)) | (f2bf(fmaxf(acc[ct][1], 0.f)) << 16);
        o.y = f2bf(fmaxf(acc[ct][2], 0.f)) | (f2bf(fmaxf(acc[ct][3], 0.f)) << 16);
        Y[((size_t)rb * 8 + ct) * 64 + l] = o;
    }
}

// ---------- pa_gemm: partial[b][g][c] = sum_{v in chunk} count(v,g) * Y[v][c] ----------
__global__ __launch_bounds__(256) void pa_gemm(
    const uint2* __restrict__ Ybf, const unsigned int* __restrict__ PA32,
    float4* __restrict__ partial, int N, int chunk)
{
    __shared__ float sY[8 * 128];
    __shared__ unsigned int sPA[8 * 16];

    int b = blockIdx.x;
    int v0 = b * chunk;
    int v1 = v0 + chunk; if (v1 > N) v1 = N;

    int t = threadIdx.x;
    int j = t & 15, dgrp = t >> 4;
    float4 acc[4][2];
    #pragma unroll
    for (int i = 0; i < 4; ++i) { acc[i][0] = make_float4(0,0,0,0); acc[i][1] = make_float4(0,0,0,0); }

    int ctS = t >> 5, lsub = t & 31;        // staging coords
    int vlocS = (lsub >> 4) * 4;
    int cS = ctS * 16 + (lsub & 15);

    for (int vc = v0; vc < v1; vc += 8) {
        {
            int rb = vc >> 4, qb = vc & 15; // qb in {0,8}
            u32x2 u = nt_ld_u2(&Ybf[((size_t)rb * 8 + ctS) * 64 + (qb >> 2) * 16 + lsub]);
            sY[(vlocS + 0) * 128 + cS] = bflo(u.x);
            sY[(vlocS + 1) * 128 + cS] = bfhi(u.x);
            sY[(vlocS + 2) * 128 + cS] = bflo(u.y);
            sY[(vlocS + 3) * 128 + cS] = bfhi(u.y);
        }
        if (t < 128) {
            int vp = vc + (t >> 4);
            sPA[t] = (vp < v1) ? nt_ld_u(&PA32[(size_t)vp * 16 + (t & 15)]) : 0u;
        }
        __syncthreads();
        const float4* sY4 = (const float4*)sY;
        #pragma unroll
        for (int vv = 0; vv < 8; ++vv) {
            unsigned int pw = sPA[vv * 16 + j];
            float4 y0 = sY4[vv * 32 + dgrp * 2 + 0];
            float4 y1 = sY4[vv * 32 + dgrp * 2 + 1];
            #pragma unroll
            for (int i = 0; i < 4; ++i) {
                float w = (float)((pw >> (i * 8)) & 0xffu);
                acc[i][0].x += w * y0.x; acc[i][0].y += w * y0.y;
                acc[i][0].z += w * y0.z; acc[i][0].w += w * y0.w;
                acc[i][1].x += w * y1.x; acc[i][1].y += w * y1.y;
                acc[i][1].z += w * y1.z; acc[i][1].w += w * y1.w;
            }
        }
        __syncthreads();
    }

    #pragma unroll
    for (int i = 0; i < 4; ++i) {
        int g = j * 4 + i;
        partial[(size_t)b * 2048 + g * 32 + dgrp * 2 + 0] = acc[i][0];
        partial[(size_t)b * 2048 + g * 32 + dgrp * 2 + 1] = acc[i][1];
    }
}

__global__ __launch_bounds__(256) void reduce_partial(
    const float* __restrict__ partial, float* __restrict__ pooled)
{
    int o = blockIdx.x * 256 + threadIdx.x; // 0..8191
    float s = 0.f;
    #pragma unroll 4
    for (int b = 0; b < PA_NB; ++b)
        s += partial[(size_t)b * 8192 + o];
    pooled[o] = s;
}

// ---------- fused tail: W23 = W2@W3 (LDS); out = sigmoid((pooled/cnt)@W23) ----------
__global__ __launch_bounds__(1024) void final_fused(
    const float* __restrict__ pooled, const int* __restrict__ gid, int N,
    const float* __restrict__ W2, const float* __restrict__ W3,
    float* __restrict__ out)
{
    __shared__ float sW23[128 * 16];
    __shared__ int lb[65];
    int t = threadIdx.x;
    if (t <= 64) {
        int lo = 0, hi = N;
        while (lo < hi) { int mid = (lo + hi) >> 1; if (gid[mid] < t) lo = mid + 1; else hi = mid; }
        lb[t] = lo;
    }
    for (int idx = t; idx < 2048; idx += 1024) {
        int k = idx >> 4, o = idx & 15;
        float a = 0.f;
        #pragma unroll 16
        for (int jj = 0; jj < 128; ++jj)
            a += W2[k * 128 + jj] * W3[jj * 16 + o];
        sW23[idx] = a;
    }
    __syncthreads();
    int g = t >> 4, o = t & 15;
    float cnt = fmaxf((float)(lb[g + 1] - lb[g]), 1.0f);
    float acc = 0.f;
    #pragma unroll 16
    for (int k = 0; k < 128; ++k)
        acc += pooled[g * 128 + k] * sW23[k * 16 + o];
    acc /= cnt;
    out[g * 16 + o] = 1.0f / (1.0f + __expf(-acc));
}

extern "C" void kernel_launch(void* const* d_in, const int* in_sizes, int n_in,
                              void* d_out, int out_size, void* d_ws, size_t ws_size,
                              hipStream_t stream)
{
    const float* features = (const float*)d_in[0];
    const float* W1       = (const float*)d_in[1];
    const float* W2       = (const float*)d_in[2];
    const float* W3       = (const float*)d_in[3];
    const int*   src      = (const int*)d_in[4];
    const int*   dst      = (const int*)d_in[5];
    const int*   gid      = (const int*)d_in[6];
    int N = in_sizes[0] / 128;
    int E = in_sizes[4];
    float* out = (float*)d_out;

    int RB = (N + 15) / 16;

    char* ws = (char*)d_ws;
    size_t p = 0;
    auto alloc = [&](size_t bytes) { void* r = ws + p; p = (p + bytes + 255) & ~(size_t)255; return r; };
    unsigned int* fbf  = (unsigned int*)alloc((size_t)N * 128 * 2);     // features bf16
    unsigned int* tbf  = (unsigned int*)alloc((size_t)N * 128 * 2);     // t bf16
    uint2*        Ybf  = (uint2*)alloc((size_t)RB * 8 * 64 * 8);        // Y bf16 frag-native
    unsigned int* PA32 = (unsigned int*)alloc((size_t)N * 16 * 4);      // packed counts
    float* partial = (float*)alloc((size_t)PA_NB * 8192 * 4);           // 8 MB
    float* pooled  = (float*)alloc(64 * 128 * sizeof(float));
    int*   cnt     = (int*)alloc((size_t)N * sizeof(int));
    int*   col     = (int*)alloc((size_t)N * CSLOT * sizeof(int));      // 12.8 MB
    int*   ovd     = (int*)alloc((size_t)OVCAP * sizeof(int));
    int*   ovs     = (int*)alloc((size_t)OVCAP * sizeof(int));
    int*   ov_cnt  = (int*)alloc(256);

    int aggGrid  = (N + 15) / 16;
    int xcdGrid  = 2048;            // 256 blocks/XCD slot -> 8 blocks/CU
    int gGrid    = (RB + 3) / 4;
    int paChunk  = (((N + PA_NB - 1) / PA_NB) + 15) & ~15;
    long long n8 = (long long)N * 16;

    // ---- features -> bf16 ----
    fconv<<<(int)((n8 + 255) / 256), 256, 0, stream>>>((const float4*)features, (uint4*)fbf, n8);

    // ---- CSR fill (fixed slots) + PA counts ----
    (void)hipMemsetAsync(cnt, 0, (size_t)N * sizeof(int), stream);
    (void)hipMemsetAsync(ov_cnt, 0, 256, stream);
    (void)hipMemsetAsync(PA32, 0, (size_t)N * 16 * 4, stream);
    fillfix_xcd<<<xcdGrid, 256, 0, stream>>>(src, dst, cnt, col, ovd, ovs, ov_cnt, E, N);
    edge_pa<<<xcdGrid, 256, 0, stream>>>(src, dst, gid, PA32, E, N);

    // ---- t = agg(features_bf16) [bf16]; Y = relu(t @ W1) [bf16 frag] ----
    csr_agg_bf16<<<aggGrid, 256, 0, stream>>>((const uint4*)fbf, cnt, col, ovd, ovs, ov_cnt, (uint4*)tbf, N);
    gemm_mfma<<<gGrid, 256, 0, stream>>>((const uint4*)tbf, W1, Ybf, N, RB);

    // ---- pooled_q = PA^T . Y ----
    pa_gemm<<<PA_NB, 256, 0, stream>>>(Ybf, PA32, (float4*)partial, N, paChunk);
    reduce_partial<<<32, 256, 0, stream>>>(partial, pooled);

    // ---- fused (W2@W3) + mean + sigmoid ----
    final_fused<<<1, 1024, 0, stream>>>(pooled, gid, N, W2, W3, out);
}